// Round 14
// baseline (73.326 us; speedup 1.0000x reference)
//
#include <hip/hip_runtime.h>
#include <hip/hip_bf16.h>

#define NN 1024   // nodes
#define HD 128    // hidden dim
#define NE 32768  // edges
#define CAP 128   // per-row neighbor capacity (Poisson(32): P(>127) ~ 1e-40)

// Device float buffers are fp32 (established R1/R7 NaN experiment).
// A_hat (X W) = (A_hat X) W -> mm0 folded into layer1.
// Edge fill: edge-parallel global atomics + tiny zero kernel (R10/R13 proven).
// R14: float4 lanes (32 lanes/node, 8 nodes/block) per G13 vectorization.

static __device__ __forceinline__ float4 f4fma(float a, float4 b, float4 c) {
    c.x = fmaf(a, b.x, c.x); c.y = fmaf(a, b.y, c.y);
    c.z = fmaf(a, b.z, c.z); c.w = fmaf(a, b.w, c.w);
    return c;
}
static __device__ __forceinline__ float4 f4add(float4 a, float4 b) {
    return make_float4(a.x + b.x, a.y + b.y, a.z + b.z, a.w + b.w);
}

__global__ __launch_bounds__(256) void k_zero(int* __restrict__ deg) {
    deg[blockIdx.x * 256 + threadIdx.x] = 0;     // grid 4 x 256 = 1024
}

// ---- k_fill: blocks 0..127 edge fill (1 edge/thread, global atomics);
//      blocks 128..191 transpose dp_w1 -> At/Bt ----
__global__ __launch_bounds__(256) void k_fill(const int* __restrict__ ei,
                                              const float* __restrict__ dpw1,
                                              int* __restrict__ deg,
                                              int* __restrict__ col,
                                              float* __restrict__ At,
                                              float* __restrict__ Bt) {
    int t = threadIdx.x;
    if (blockIdx.x < 128) {
        int e = blockIdx.x * 256 + t;            // 32768 threads, 1 edge each
        int dst = ei[NE + e];
        int slot = atomicAdd(&deg[dst], 1);
        if (slot < CAP) col[dst * CAP + slot] = ei[e];
    } else {
        int i = (blockIdx.x - 128) * 256 + t;    // 16384 threads, 2 elems each
        for (; i < HD * 2 * HD; i += 64 * 256) {
            int h = i >> 8, k = i & 255;         // dp_w1 [128][256]
            float v = dpw1[i];                   // coalesced read
            if (k < HD) At[k * HD + h] = v;      // scatter write (small)
            else        Bt[(k - HD) * HD + h] = v;
        }
    }
}

// ---- layer1: gather RAW x (per-neighbor dinv, LDS table) -> @W0+b0 -> relu
//      -> s1 = dinv*relu(h1). 8 nodes/block, 32 lanes x float4 per node. ----
__global__ __launch_bounds__(256) void k_l1(const float* __restrict__ x,
                                            const int* __restrict__ deg,
                                            const int* __restrict__ col,
                                            const float* __restrict__ W0,
                                            const float* __restrict__ b0,
                                            float* __restrict__ s1out) {
    __shared__ float sdinv[NN];       // 4KB
    __shared__ float agg[8][HD];      // 4KB
    __shared__ int   scol[8][CAP];    // 4KB
    int t = threadIdx.x;
    int q = t >> 5, l = t & 31;
    int n = blockIdx.x * 8 + q;
    for (int i = t; i < NN; i += 256) sdinv[i] = rsqrtf((float)min(deg[i], CAP) + 1.f);
    int cnt = min(deg[n], CAP);
    for (int i = l; i < cnt; i += 32) scol[q][i] = col[n * CAP + i];
    __syncthreads();
    const float4* x4 = (const float4*)x;        // row stride 32 float4
    float dvn = sdinv[n];
    float4 z = make_float4(0.f, 0.f, 0.f, 0.f);
    float4 s0 = z, s1 = z, s2 = z, s3 = z;
    int i = 0;
    for (; i + 3 < cnt; i += 4) {
        int c0 = scol[q][i + 0], c1 = scol[q][i + 1];
        int c2 = scol[q][i + 2], c3 = scol[q][i + 3];
        s0 = f4fma(sdinv[c0], x4[c0 * 32 + l], s0);
        s1 = f4fma(sdinv[c1], x4[c1 * 32 + l], s1);
        s2 = f4fma(sdinv[c2], x4[c2 * 32 + l], s2);
        s3 = f4fma(sdinv[c3], x4[c3 * 32 + l], s3);
    }
    for (; i < cnt; i++) { int c = scol[q][i]; s0 = f4fma(sdinv[c], x4[c * 32 + l], s0); }
    float4 s = f4fma(dvn, x4[n * 32 + l], f4add(f4add(s0, s1), f4add(s2, s3)));
    agg[q][4 * l + 0] = dvn * s.x;
    agg[q][4 * l + 1] = dvn * s.y;
    agg[q][4 * l + 2] = dvn * s.z;
    agg[q][4 * l + 3] = dvn * s.w;
    __syncthreads();
    const float4* W4 = (const float4*)W0;       // [k][32 float4]
    float4 acc = ((const float4*)b0)[l];
#pragma unroll 8
    for (int k = 0; k < HD; k++) acc = f4fma(agg[q][k], W4[k * 32 + l], acc);
    float4 r;
    r.x = dvn * fmaxf(acc.x, 0.f);
    r.y = dvn * fmaxf(acc.y, 0.f);
    r.z = dvn * fmaxf(acc.z, 0.f);
    r.w = dvn * fmaxf(acc.w, 0.f);
    ((float4*)s1out)[n * 32 + l] = r;
}

// ---- layer2: plain-sum gather of pre-scaled s1 -> @W1+b1 -> relu -> s2 ----
__global__ __launch_bounds__(256) void k_l2(const float* __restrict__ s1in,
                                            const int* __restrict__ deg,
                                            const int* __restrict__ col,
                                            const float* __restrict__ W1,
                                            const float* __restrict__ b1,
                                            float* __restrict__ s2out) {
    __shared__ float agg[8][HD];
    __shared__ int   scol[8][CAP];
    int t = threadIdx.x;
    int q = t >> 5, l = t & 31;
    int n = blockIdx.x * 8 + q;
    int cnt = min(deg[n], CAP);
    float dvn = rsqrtf((float)cnt + 1.f);
    for (int i = l; i < cnt; i += 32) scol[q][i] = col[n * CAP + i];
    __syncthreads();
    const float4* y4 = (const float4*)s1in;
    float4 z = make_float4(0.f, 0.f, 0.f, 0.f);
    float4 s0 = z, s1 = z, s2 = z, s3 = z;
    int i = 0;
    for (; i + 3 < cnt; i += 4) {
        int c0 = scol[q][i + 0], c1 = scol[q][i + 1];
        int c2 = scol[q][i + 2], c3 = scol[q][i + 3];
        s0 = f4add(s0, y4[c0 * 32 + l]);
        s1 = f4add(s1, y4[c1 * 32 + l]);
        s2 = f4add(s2, y4[c2 * 32 + l]);
        s3 = f4add(s3, y4[c3 * 32 + l]);
    }
    for (; i < cnt; i++) s0 = f4add(s0, y4[scol[q][i] * 32 + l]);
    float4 s = f4add(y4[n * 32 + l], f4add(f4add(s0, s1), f4add(s2, s3)));
    agg[q][4 * l + 0] = dvn * s.x;
    agg[q][4 * l + 1] = dvn * s.y;
    agg[q][4 * l + 2] = dvn * s.z;
    agg[q][4 * l + 3] = dvn * s.w;
    __syncthreads();
    const float4* W4 = (const float4*)W1;
    float4 acc = ((const float4*)b1)[l];
#pragma unroll 8
    for (int k = 0; k < HD; k++) acc = f4fma(agg[q][k], W4[k * 32 + l], acc);
    float4 r;
    r.x = dvn * fmaxf(acc.x, 0.f);
    r.y = dvn * fmaxf(acc.y, 0.f);
    r.z = dvn * fmaxf(acc.z, 0.f);
    r.w = dvn * fmaxf(acc.w, 0.f);
    ((float4*)s2out)[n * 32 + l] = r;
}

// ---- final: gather s2 -> @W2+b2 (no relu) -> emb=@out_w+out_b -> u,v ----
__global__ __launch_bounds__(256) void k_fin(const float* __restrict__ s2in,
                                             const int* __restrict__ deg,
                                             const int* __restrict__ col,
                                             const float* __restrict__ W2,
                                             const float* __restrict__ b2,
                                             const float* __restrict__ out_w,
                                             const float* __restrict__ out_b,
                                             const float* __restrict__ At,
                                             const float* __restrict__ Bt,
                                             const float* __restrict__ dp_b1,
                                             float* __restrict__ emb_out,
                                             float* __restrict__ u,
                                             float* __restrict__ v) {
    __shared__ float bufA[8][HD];
    __shared__ float bufB[8][HD];
    __shared__ int   scol[8][CAP];
    int t = threadIdx.x;
    int q = t >> 5, l = t & 31;
    int n = blockIdx.x * 8 + q;
    int cnt = min(deg[n], CAP);
    float dvn = rsqrtf((float)cnt + 1.f);
    for (int i = l; i < cnt; i += 32) scol[q][i] = col[n * CAP + i];
    __syncthreads();
    const float4* y4 = (const float4*)s2in;
    float4 z = make_float4(0.f, 0.f, 0.f, 0.f);
    float4 s0 = z, s1 = z, s2 = z, s3 = z;
    int i = 0;
    for (; i + 3 < cnt; i += 4) {
        int c0 = scol[q][i + 0], c1 = scol[q][i + 1];
        int c2 = scol[q][i + 2], c3 = scol[q][i + 3];
        s0 = f4add(s0, y4[c0 * 32 + l]);
        s1 = f4add(s1, y4[c1 * 32 + l]);
        s2 = f4add(s2, y4[c2 * 32 + l]);
        s3 = f4add(s3, y4[c3 * 32 + l]);
    }
    for (; i < cnt; i++) s0 = f4add(s0, y4[scol[q][i] * 32 + l]);
    float4 s = f4add(y4[n * 32 + l], f4add(f4add(s0, s1), f4add(s2, s3)));
    bufA[q][4 * l + 0] = dvn * s.x;
    bufA[q][4 * l + 1] = dvn * s.y;
    bufA[q][4 * l + 2] = dvn * s.z;
    bufA[q][4 * l + 3] = dvn * s.w;
    __syncthreads();
    const float4* W24 = (const float4*)W2;
    float4 acc = ((const float4*)b2)[l];
#pragma unroll 8
    for (int k = 0; k < HD; k++) acc = f4fma(bufA[q][k], W24[k * 32 + l], acc);
    bufB[q][4 * l + 0] = acc.x;                 // h3 (no relu)
    bufB[q][4 * l + 1] = acc.y;
    bufB[q][4 * l + 2] = acc.z;
    bufB[q][4 * l + 3] = acc.w;
    __syncthreads();
    const float4* OW4 = (const float4*)out_w;
    float4 e = ((const float4*)out_b)[l];
#pragma unroll 8
    for (int k = 0; k < HD; k++) e = f4fma(bufB[q][k], OW4[k * 32 + l], e);
    ((float4*)emb_out)[n * 32 + l] = e;
    bufA[q][4 * l + 0] = e.x;                   // emb (bufA reusable)
    bufA[q][4 * l + 1] = e.y;
    bufA[q][4 * l + 2] = e.z;
    bufA[q][4 * l + 3] = e.w;
    __syncthreads();
    const float4* At4 = (const float4*)At;
    const float4* Bt4 = (const float4*)Bt;
    float4 uu = ((const float4*)dp_b1)[l];      // fold dp_b1 into u
    float4 vv = z;
#pragma unroll 8
    for (int k = 0; k < HD; k++) {
        float em = bufA[q][k];
        uu = f4fma(em, At4[k * 32 + l], uu);
        vv = f4fma(em, Bt4[k * 32 + l], vv);
    }
    ((float4*)u)[n * 32 + l] = uu;
    ((float4*)v)[n * 32 + l] = vv;
}

// ---- pairwise: upper-triangle 32x32 tiles, mirrored writes ----
__global__ __launch_bounds__(256) void k_pair(const float* __restrict__ u,
                                              const float* __restrict__ v,
                                              const float* __restrict__ w2,
                                              const float* __restrict__ b2v,
                                              float* __restrict__ dist) {
    __shared__ float4 su4[32 * 32];
    __shared__ float4 sv4[32 * 32];
    __shared__ float4 sw24[32];
    __shared__ float sp[32][33];

    int t = threadIdx.x;
    int rem = blockIdx.x, bi = 0;
    while (rem >= 32 - bi) { rem -= 32 - bi; bi++; }
    int bj = bi + rem;
    int i0 = bi * 32, j0 = bj * 32;

#pragma unroll
    for (int r = 0; r < 4; r++) {
        int p = t + r * 256;
        int rowp = p >> 5, c = p & 31;
        su4[p] = *(const float4*)(u + (size_t)(i0 + rowp) * HD + (c << 2));
        sv4[c * 32 + rowp] = *(const float4*)(v + (size_t)(j0 + rowp) * HD + (c << 2));
    }
    if (t < 32) sw24[t] = *(const float4*)(w2 + 4 * t);
    __syncthreads();

    int jl = t & 31, ib = t >> 5;
    float acc0 = 0.f, acc1 = 0.f, acc2 = 0.f, acc3 = 0.f;
    for (int c = 0; c < 32; c++) {
        float4 vv = sv4[c * 32 + jl];
        float4 w4 = sw24[c];
        float4 a0 = su4[(ib * 4 + 0) * 32 + c];
        float4 a1 = su4[(ib * 4 + 1) * 32 + c];
        float4 a2 = su4[(ib * 4 + 2) * 32 + c];
        float4 a3 = su4[(ib * 4 + 3) * 32 + c];
        acc0 += fmaxf(a0.x + vv.x, 0.f) * w4.x + fmaxf(a0.y + vv.y, 0.f) * w4.y +
                fmaxf(a0.z + vv.z, 0.f) * w4.z + fmaxf(a0.w + vv.w, 0.f) * w4.w;
        acc1 += fmaxf(a1.x + vv.x, 0.f) * w4.x + fmaxf(a1.y + vv.y, 0.f) * w4.y +
                fmaxf(a1.z + vv.z, 0.f) * w4.z + fmaxf(a1.w + vv.w, 0.f) * w4.w;
        acc2 += fmaxf(a2.x + vv.x, 0.f) * w4.x + fmaxf(a2.y + vv.y, 0.f) * w4.y +
                fmaxf(a2.z + vv.z, 0.f) * w4.z + fmaxf(a2.w + vv.w, 0.f) * w4.w;
        acc3 += fmaxf(a3.x + vv.x, 0.f) * w4.x + fmaxf(a3.y + vv.y, 0.f) * w4.y +
                fmaxf(a3.z + vv.z, 0.f) * w4.z + fmaxf(a3.w + vv.w, 0.f) * w4.w;
    }
    float bb2 = b2v[0];
    float pr0 = 1.f / (1.f + __expf(-(acc0 + bb2)));
    float pr1 = 1.f / (1.f + __expf(-(acc1 + bb2)));
    float pr2 = 1.f / (1.f + __expf(-(acc2 + bb2)));
    float pr3 = 1.f / (1.f + __expf(-(acc3 + bb2)));
    sp[ib * 4 + 0][jl] = pr0;
    sp[ib * 4 + 1][jl] = pr1;
    sp[ib * 4 + 2][jl] = pr2;
    sp[ib * 4 + 3][jl] = pr3;
    __syncthreads();

    if (bi < bj) {
        dist[(size_t)(i0 + ib * 4 + 0) * NN + j0 + jl] = pr0;
        dist[(size_t)(i0 + ib * 4 + 1) * NN + j0 + jl] = pr1;
        dist[(size_t)(i0 + ib * 4 + 2) * NN + j0 + jl] = pr2;
        dist[(size_t)(i0 + ib * 4 + 3) * NN + j0 + jl] = pr3;
#pragma unroll
        for (int p = 0; p < 4; p++) {
            int jrow = ib * 4 + p;
            dist[(size_t)(j0 + jrow) * NN + i0 + jl] = sp[jl][jrow];
        }
    } else {
#pragma unroll
        for (int p = 0; p < 4; p++) {
            int il = ib * 4 + p;
            float val = (il < jl) ? sp[il][jl] : ((il > jl) ? sp[jl][il] : 0.f);
            dist[(size_t)(i0 + il) * NN + j0 + jl] = val;
        }
    }
}

extern "C" void kernel_launch(void* const* d_in, const int* in_sizes, int n_in,
                              void* d_out, int out_size, void* d_ws, size_t ws_size,
                              hipStream_t stream) {
    const float* x    = (const float*)d_in[0];
    const int*   ei   = (const int*)d_in[1];
    const float* w0   = (const float*)d_in[2];
    const float* b0   = (const float*)d_in[3];
    const float* w1   = (const float*)d_in[4];
    const float* b1c  = (const float*)d_in[5];
    const float* w2c  = (const float*)d_in[6];
    const float* b2c  = (const float*)d_in[7];
    const float* ow   = (const float*)d_in[8];
    const float* ob   = (const float*)d_in[9];
    const float* dpw1 = (const float*)d_in[10];
    const float* dpb1 = (const float*)d_in[11];
    const float* dpw2 = (const float*)d_in[12];
    const float* dpb2 = (const float*)d_in[13];

    float* out_emb  = (float*)d_out;
    float* out_dist = out_emb + (size_t)NN * HD;

    char* p = (char*)d_ws;
    auto take = [&](size_t bytes) { void* r = p; p += (bytes + 255) & ~(size_t)255; return r; };
    int*   deg = (int*)take(NN * 4);
    int*   col = (int*)take(NN * CAP * 4);
    float* yA  = (float*)take(NN * HD * 4);
    float* yB  = (float*)take(NN * HD * 4);
    float* u   = (float*)take(NN * HD * 4);
    float* v   = (float*)take(NN * HD * 4);
    float* At  = (float*)take(HD * HD * 4);
    float* Bt  = (float*)take(HD * HD * 4);

    k_zero<<<4, 256, 0, stream>>>(deg);
    k_fill<<<192, 256, 0, stream>>>(ei, dpw1, deg, col, At, Bt);
    k_l1<<<128, 256, 0, stream>>>(x, deg, col, w0, b0, yA);
    k_l2<<<128, 256, 0, stream>>>(yA, deg, col, w1, b1c, yB);
    k_fin<<<128, 256, 0, stream>>>(yB, deg, col, w2c, b2c, ow, ob, At, Bt, dpb1,
                                   out_emb, u, v);
    k_pair<<<(32 * 33) / 2, 256, 0, stream>>>(u, v, dpw2, dpb2, out_dist);
}

// Round 15
// 57.297 us; speedup vs baseline: 1.2798x; 1.2798x over previous
//
#include <hip/hip_runtime.h>
#include <hip/hip_bf16.h>

#define NN 1024   // nodes
#define HD 128    // hidden dim
#define NE 32768  // edges
#define CAP 128   // per-row neighbor capacity (Poisson(32): P(>127) ~ 1e-40)

// Device float buffers are fp32 (R1/R7 NaN experiment).
// A_hat (X W) = (A_hat X) W -> mm0 folded into layer1.
// R14 lesson: keep >=2048 waves (512 blocks x 256): TLP is the latency hider.
// R15: float4 gather via 4 lane-groups per node + LDS reduce, same wave count.

static __device__ __forceinline__ float4 f4fma(float a, float4 b, float4 c) {
    c.x = fmaf(a, b.x, c.x); c.y = fmaf(a, b.y, c.y);
    c.z = fmaf(a, b.z, c.z); c.w = fmaf(a, b.w, c.w);
    return c;
}
static __device__ __forceinline__ float4 f4add(float4 a, float4 b) {
    return make_float4(a.x + b.x, a.y + b.y, a.z + b.z, a.w + b.w);
}

__global__ __launch_bounds__(256) void k_zero(int* __restrict__ deg) {
    deg[blockIdx.x * 256 + threadIdx.x] = 0;     // grid 4 x 256 = 1024
}

// ---- k_fill: blocks 0..127 edge fill (1 edge/thread, global atomics);
//      blocks 128..191 transpose dp_w1 -> At/Bt ----
__global__ __launch_bounds__(256) void k_fill(const int* __restrict__ ei,
                                              const float* __restrict__ dpw1,
                                              int* __restrict__ deg,
                                              int* __restrict__ col,
                                              float* __restrict__ At,
                                              float* __restrict__ Bt) {
    int t = threadIdx.x;
    if (blockIdx.x < 128) {
        int e = blockIdx.x * 256 + t;            // 32768 threads, 1 edge each
        int dst = ei[NE + e];
        int slot = atomicAdd(&deg[dst], 1);
        if (slot < CAP) col[dst * CAP + slot] = ei[e];
    } else {
        int i = (blockIdx.x - 128) * 256 + t;    // 16384 threads, 2 elems each
        for (; i < HD * 2 * HD; i += 64 * 256) {
            int h = i >> 8, k = i & 255;         // dp_w1 [128][256]
            float v = dpw1[i];                   // coalesced read
            if (k < HD) At[k * HD + h] = v;      // scatter write (small)
            else        Bt[(k - HD) * HD + h] = v;
        }
    }
}

// Gather macro body: group g (of 4) covers neighbors i==g (mod 4), float4/lane.
// part layout: part[half][g][128] floats (stored as float4 per lane).

// ---- layer1: gather RAW x (per-neighbor dinv) -> @W0+b0 -> relu -> s1 ----
__global__ __launch_bounds__(256) void k_l1(const float* __restrict__ x,
                                            const int* __restrict__ deg,
                                            const int* __restrict__ col,
                                            const float* __restrict__ W0,
                                            const float* __restrict__ b0,
                                            float* __restrict__ s1out) {
    __shared__ float sdinv[NN];          // 4KB
    __shared__ float part[2 * 4 * HD];   // 4KB
    __shared__ float agg[2][HD];         // 1KB
    __shared__ int   scol[2][CAP];       // 1KB
    int t = threadIdx.x;
    int half = t >> 7, h = t & 127;
    int g = (t >> 5) & 3, l = t & 31;
    int n = blockIdx.x * 2 + half;
    for (int i = t; i < NN; i += 256) sdinv[i] = rsqrtf((float)min(deg[i], CAP) + 1.f);
    int cnt = min(deg[n], CAP);
    for (int i = h; i < cnt; i += 128) scol[half][i] = col[n * CAP + i];
    __syncthreads();
    const float4* x4 = (const float4*)x;         // node row = 32 float4
    float4 z = make_float4(0.f, 0.f, 0.f, 0.f);
    float4 s0 = z, s1 = z, s2 = z, s3 = z;
    int i = g;
    for (; i + 12 < cnt; i += 16) {
        int c0 = scol[half][i], c1 = scol[half][i + 4];
        int c2 = scol[half][i + 8], c3 = scol[half][i + 12];
        s0 = f4fma(sdinv[c0], x4[c0 * 32 + l], s0);
        s1 = f4fma(sdinv[c1], x4[c1 * 32 + l], s1);
        s2 = f4fma(sdinv[c2], x4[c2 * 32 + l], s2);
        s3 = f4fma(sdinv[c3], x4[c3 * 32 + l], s3);
    }
    for (; i < cnt; i += 4) { int c = scol[half][i]; s0 = f4fma(sdinv[c], x4[c * 32 + l], s0); }
    float4 ps = f4add(f4add(s0, s1), f4add(s2, s3));
    *((float4*)&part[((half << 2) + g) * HD + 4 * l]) = ps;
    __syncthreads();
    float dvn = sdinv[n];
    float s = dvn * x[n * HD + h]
            + part[(half << 2) * HD + h]       + part[((half << 2) + 1) * HD + h]
            + part[((half << 2) + 2) * HD + h] + part[((half << 2) + 3) * HD + h];
    agg[half][h] = dvn * s;
    __syncthreads();
    float acc = b0[h];
#pragma unroll 8
    for (int k = 0; k < HD; k++) acc += agg[half][k] * W0[k * HD + h];
    s1out[n * HD + h] = dvn * fmaxf(acc, 0.f);   // dinv * relu(h1)
}

// ---- layer2: plain-sum gather of pre-scaled s1 -> @W1+b1 -> relu -> s2 ----
__global__ __launch_bounds__(256) void k_l2(const float* __restrict__ s1in,
                                            const int* __restrict__ deg,
                                            const int* __restrict__ col,
                                            const float* __restrict__ W1,
                                            const float* __restrict__ b1,
                                            float* __restrict__ s2out) {
    __shared__ float part[2 * 4 * HD];
    __shared__ float agg[2][HD];
    __shared__ int   scol[2][CAP];
    int t = threadIdx.x;
    int half = t >> 7, h = t & 127;
    int g = (t >> 5) & 3, l = t & 31;
    int n = blockIdx.x * 2 + half;
    int cnt = min(deg[n], CAP);
    float dvn = rsqrtf((float)cnt + 1.f);
    for (int i = h; i < cnt; i += 128) scol[half][i] = col[n * CAP + i];
    __syncthreads();
    const float4* y4 = (const float4*)s1in;
    float4 z = make_float4(0.f, 0.f, 0.f, 0.f);
    float4 s0 = z, s1 = z, s2 = z, s3 = z;
    int i = g;
    for (; i + 12 < cnt; i += 16) {
        int c0 = scol[half][i], c1 = scol[half][i + 4];
        int c2 = scol[half][i + 8], c3 = scol[half][i + 12];
        s0 = f4add(s0, y4[c0 * 32 + l]);
        s1 = f4add(s1, y4[c1 * 32 + l]);
        s2 = f4add(s2, y4[c2 * 32 + l]);
        s3 = f4add(s3, y4[c3 * 32 + l]);
    }
    for (; i < cnt; i += 4) s0 = f4add(s0, y4[scol[half][i] * 32 + l]);
    float4 ps = f4add(f4add(s0, s1), f4add(s2, s3));
    *((float4*)&part[((half << 2) + g) * HD + 4 * l]) = ps;
    __syncthreads();
    float s = s1in[n * HD + h]
            + part[(half << 2) * HD + h]       + part[((half << 2) + 1) * HD + h]
            + part[((half << 2) + 2) * HD + h] + part[((half << 2) + 3) * HD + h];
    agg[half][h] = dvn * s;
    __syncthreads();
    float acc = b1[h];
#pragma unroll 8
    for (int k = 0; k < HD; k++) acc += agg[half][k] * W1[k * HD + h];
    s2out[n * HD + h] = dvn * fmaxf(acc, 0.f);
}

// ---- final: gather s2 -> @W2+b2 (no relu) -> emb=@out_w+out_b -> u,v ----
__global__ __launch_bounds__(256) void k_fin(const float* __restrict__ s2in,
                                             const int* __restrict__ deg,
                                             const int* __restrict__ col,
                                             const float* __restrict__ W2,
                                             const float* __restrict__ b2,
                                             const float* __restrict__ out_w,
                                             const float* __restrict__ out_b,
                                             const float* __restrict__ At,
                                             const float* __restrict__ Bt,
                                             const float* __restrict__ dp_b1,
                                             float* __restrict__ emb_out,
                                             float* __restrict__ u,
                                             float* __restrict__ v) {
    __shared__ float part[2 * 4 * HD];   // also reused as bufB (h3)
    __shared__ float bufA[2][HD];
    __shared__ int   scol[2][CAP];
    int t = threadIdx.x;
    int half = t >> 7, h = t & 127;
    int g = (t >> 5) & 3, l = t & 31;
    int n = blockIdx.x * 2 + half;
    int cnt = min(deg[n], CAP);
    float dvn = rsqrtf((float)cnt + 1.f);
    for (int i = h; i < cnt; i += 128) scol[half][i] = col[n * CAP + i];
    __syncthreads();
    const float4* y4 = (const float4*)s2in;
    float4 z = make_float4(0.f, 0.f, 0.f, 0.f);
    float4 s0 = z, s1 = z, s2 = z, s3 = z;
    int i = g;
    for (; i + 12 < cnt; i += 16) {
        int c0 = scol[half][i], c1 = scol[half][i + 4];
        int c2 = scol[half][i + 8], c3 = scol[half][i + 12];
        s0 = f4add(s0, y4[c0 * 32 + l]);
        s1 = f4add(s1, y4[c1 * 32 + l]);
        s2 = f4add(s2, y4[c2 * 32 + l]);
        s3 = f4add(s3, y4[c3 * 32 + l]);
    }
    for (; i < cnt; i += 4) s0 = f4add(s0, y4[scol[half][i] * 32 + l]);
    float4 ps = f4add(f4add(s0, s1), f4add(s2, s3));
    *((float4*)&part[((half << 2) + g) * HD + 4 * l]) = ps;
    __syncthreads();
    float s = s2in[n * HD + h]
            + part[(half << 2) * HD + h]       + part[((half << 2) + 1) * HD + h]
            + part[((half << 2) + 2) * HD + h] + part[((half << 2) + 3) * HD + h];
    bufA[half][h] = dvn * s;                    // agg2
    __syncthreads();
    float acc = b2[h];
#pragma unroll 8
    for (int k = 0; k < HD; k++) acc += bufA[half][k] * W2[k * HD + h];
    __syncthreads();                            // part readers done
    part[half * HD + h] = acc;                  // h3 (no relu), reuse part[0..2*HD)
    __syncthreads();
    float e = out_b[h];
#pragma unroll 8
    for (int k = 0; k < HD; k++) e += part[half * HD + k] * out_w[k * HD + h];
    emb_out[n * HD + h] = e;
    __syncthreads();
    bufA[half][h] = e;                          // emb
    __syncthreads();
    float uu = dp_b1[h], vv = 0.f;              // fold dp_b1 into u
#pragma unroll 8
    for (int k = 0; k < HD; k++) {
        float em = bufA[half][k];
        uu += em * At[k * HD + h];              // coalesced
        vv += em * Bt[k * HD + h];
    }
    u[n * HD + h] = uu;
    v[n * HD + h] = vv;
}

// ---- pairwise: upper-triangle 32x32 tiles, mirrored writes ----
__global__ __launch_bounds__(256) void k_pair(const float* __restrict__ u,
                                              const float* __restrict__ v,
                                              const float* __restrict__ w2,
                                              const float* __restrict__ b2v,
                                              float* __restrict__ dist) {
    __shared__ float4 su4[32 * 32];
    __shared__ float4 sv4[32 * 32];
    __shared__ float4 sw24[32];
    __shared__ float sp[32][33];

    int t = threadIdx.x;
    int rem = blockIdx.x, bi = 0;
    while (rem >= 32 - bi) { rem -= 32 - bi; bi++; }
    int bj = bi + rem;
    int i0 = bi * 32, j0 = bj * 32;

#pragma unroll
    for (int r = 0; r < 4; r++) {
        int p = t + r * 256;
        int rowp = p >> 5, c = p & 31;
        su4[p] = *(const float4*)(u + (size_t)(i0 + rowp) * HD + (c << 2));
        sv4[c * 32 + rowp] = *(const float4*)(v + (size_t)(j0 + rowp) * HD + (c << 2));
    }
    if (t < 32) sw24[t] = *(const float4*)(w2 + 4 * t);
    __syncthreads();

    int jl = t & 31, ib = t >> 5;
    float acc0 = 0.f, acc1 = 0.f, acc2 = 0.f, acc3 = 0.f;
    for (int c = 0; c < 32; c++) {
        float4 vv = sv4[c * 32 + jl];
        float4 w4 = sw24[c];
        float4 a0 = su4[(ib * 4 + 0) * 32 + c];
        float4 a1 = su4[(ib * 4 + 1) * 32 + c];
        float4 a2 = su4[(ib * 4 + 2) * 32 + c];
        float4 a3 = su4[(ib * 4 + 3) * 32 + c];
        acc0 += fmaxf(a0.x + vv.x, 0.f) * w4.x + fmaxf(a0.y + vv.y, 0.f) * w4.y +
                fmaxf(a0.z + vv.z, 0.f) * w4.z + fmaxf(a0.w + vv.w, 0.f) * w4.w;
        acc1 += fmaxf(a1.x + vv.x, 0.f) * w4.x + fmaxf(a1.y + vv.y, 0.f) * w4.y +
                fmaxf(a1.z + vv.z, 0.f) * w4.z + fmaxf(a1.w + vv.w, 0.f) * w4.w;
        acc2 += fmaxf(a2.x + vv.x, 0.f) * w4.x + fmaxf(a2.y + vv.y, 0.f) * w4.y +
                fmaxf(a2.z + vv.z, 0.f) * w4.z + fmaxf(a2.w + vv.w, 0.f) * w4.w;
        acc3 += fmaxf(a3.x + vv.x, 0.f) * w4.x + fmaxf(a3.y + vv.y, 0.f) * w4.y +
                fmaxf(a3.z + vv.z, 0.f) * w4.z + fmaxf(a3.w + vv.w, 0.f) * w4.w;
    }
    float bb2 = b2v[0];
    float pr0 = 1.f / (1.f + __expf(-(acc0 + bb2)));
    float pr1 = 1.f / (1.f + __expf(-(acc1 + bb2)));
    float pr2 = 1.f / (1.f + __expf(-(acc2 + bb2)));
    float pr3 = 1.f / (1.f + __expf(-(acc3 + bb2)));
    sp[ib * 4 + 0][jl] = pr0;
    sp[ib * 4 + 1][jl] = pr1;
    sp[ib * 4 + 2][jl] = pr2;
    sp[ib * 4 + 3][jl] = pr3;
    __syncthreads();

    if (bi < bj) {
        dist[(size_t)(i0 + ib * 4 + 0) * NN + j0 + jl] = pr0;
        dist[(size_t)(i0 + ib * 4 + 1) * NN + j0 + jl] = pr1;
        dist[(size_t)(i0 + ib * 4 + 2) * NN + j0 + jl] = pr2;
        dist[(size_t)(i0 + ib * 4 + 3) * NN + j0 + jl] = pr3;
#pragma unroll
        for (int p = 0; p < 4; p++) {
            int jrow = ib * 4 + p;
            dist[(size_t)(j0 + jrow) * NN + i0 + jl] = sp[jl][jrow];
        }
    } else {
#pragma unroll
        for (int p = 0; p < 4; p++) {
            int il = ib * 4 + p;
            float val = (il < jl) ? sp[il][jl] : ((il > jl) ? sp[jl][il] : 0.f);
            dist[(size_t)(i0 + il) * NN + j0 + jl] = val;
        }
    }
}

extern "C" void kernel_launch(void* const* d_in, const int* in_sizes, int n_in,
                              void* d_out, int out_size, void* d_ws, size_t ws_size,
                              hipStream_t stream) {
    const float* x    = (const float*)d_in[0];
    const int*   ei   = (const int*)d_in[1];
    const float* w0   = (const float*)d_in[2];
    const float* b0   = (const float*)d_in[3];
    const float* w1   = (const float*)d_in[4];
    const float* b1c  = (const float*)d_in[5];
    const float* w2c  = (const float*)d_in[6];
    const float* b2c  = (const float*)d_in[7];
    const float* ow   = (const float*)d_in[8];
    const float* ob   = (const float*)d_in[9];
    const float* dpw1 = (const float*)d_in[10];
    const float* dpb1 = (const float*)d_in[11];
    const float* dpw2 = (const float*)d_in[12];
    const float* dpb2 = (const float*)d_in[13];

    float* out_emb  = (float*)d_out;
    float* out_dist = out_emb + (size_t)NN * HD;

    char* p = (char*)d_ws;
    auto take = [&](size_t bytes) { void* r = p; p += (bytes + 255) & ~(size_t)255; return r; };
    int*   deg = (int*)take(NN * 4);
    int*   col = (int*)take(NN * CAP * 4);
    float* yA  = (float*)take(NN * HD * 4);
    float* yB  = (float*)take(NN * HD * 4);
    float* u   = (float*)take(NN * HD * 4);
    float* v   = (float*)take(NN * HD * 4);
    float* At  = (float*)take(HD * HD * 4);
    float* Bt  = (float*)take(HD * HD * 4);

    k_zero<<<4, 256, 0, stream>>>(deg);
    k_fill<<<192, 256, 0, stream>>>(ei, dpw1, deg, col, At, Bt);
    k_l1<<<512, 256, 0, stream>>>(x, deg, col, w0, b0, yA);
    k_l2<<<512, 256, 0, stream>>>(yA, deg, col, w1, b1c, yB);
    k_fin<<<512, 256, 0, stream>>>(yB, deg, col, w2c, b2c, ow, ob, At, Bt, dpb1,
                                   out_emb, u, v);
    k_pair<<<(32 * 33) / 2, 256, 0, stream>>>(u, v, dpw2, dpb2, out_dist);
}